// Round 11
// baseline (204.485 us; speedup 1.0000x reference)
//
#include <hip/hip_runtime.h>
#include <hip/hip_fp16.h>

#define NQ 10000
#define BS 2
#define NV 19560
#define NH 8
#define HD 32
#define EMB 256

typedef __attribute__((ext_vector_type(8))) short bf16x8;
typedef __attribute__((ext_vector_type(8))) unsigned short u16x8;
typedef __attribute__((ext_vector_type(4))) float f32x4;
typedef __attribute__((ext_vector_type(4))) short s16x4;

__device__ __forceinline__ unsigned short f2bf(float x) {
    unsigned u = __float_as_uint(x);
    u += 0x7FFFu + ((u >> 16) & 1u);       // RNE
    return (unsigned short)(u >> 16);
}

// ---------------------------------------------------------------------------
// Transpose weights into Bt[n][k] bf16 + concat biases. [proven]
// ---------------------------------------------------------------------------
__global__ __launch_bounds__(256) void convert_W(
    const float* __restrict__ Wv, const float* __restrict__ Wo,
    const float* __restrict__ Wa, const float* __restrict__ bv,
    const float* __restrict__ bo, const float* __restrict__ ba,
    ushort* __restrict__ Bt, float* __restrict__ bias) {
    int n = blockIdx.x;      // 0..639
    int k = threadIdx.x;     // 0..255
    float x;
    if (n < 256)       x = Wv[k * 256 + n];
    else if (n < 512)  x = Wo[k * 256 + (n - 256)];
    else               x = Wa[k * 128 + (n - 512)];
    Bt[n * 256 + k] = f2bf(x);
    if (k == 0)
        bias[n] = (n < 256) ? bv[n] : (n < 512) ? bo[n - 256] : ba[n - 512];
}

// ---------------------------------------------------------------------------
// Value-projection GEMM. [FROZEN r13 body, isval constant-folded; split r18.]
// ---------------------------------------------------------------------------
__global__ __launch_bounds__(256) void gemm_val(
    const float* __restrict__ value, const ushort* __restrict__ Bt,
    const float* __restrict__ bias, ushort* __restrict__ Cv)
{
    __shared__ short As[64][40], Bhs[128][40];  // pad 32->40

    const int tid = threadIdx.x;

    // T1 remap: 1224 = 8*153 exact [r13 proven]
    const int bid0 = blockIdx.x;
    const int bid = (bid0 & 7) * 153 + (bid0 >> 3);

    const int mblk = bid >> 1, npan = bid & 1;
    const int M  = BS * NV;
    const int m0 = mblk * 64;
    const int n0 = npan * 128;

    const int arow = tid >> 2;
    const int acol = (tid & 3) * 8;
    const bool aval = (m0 + arow) < M;
    const float* Ap = value + (size_t)(m0 + arow) * 256 + acol;
    const int brow = tid >> 1;
    const int bcol = (tid & 1) * 16;
    const ushort* Bp = Bt + (size_t)(n0 + brow) * 256 + bcol;

    const int lane = tid & 63, wave = tid >> 6;
    const int wrow = (wave >> 1) * 32, wcol = (wave & 1) * 64;
    const int lr = lane & 15, quad = lane >> 4, lk = quad * 8;

    f32x4 acc[2][4] = {};

    for (int k0 = 0; k0 < 256; k0 += 32) {
        #pragma unroll
        for (int g = 0; g < 2; g++) {
            f32x4 v = {};
            if (aval) v = *(const f32x4*)(Ap + k0 + g * 4);
            s16x4 hh;
            #pragma unroll
            for (int e = 0; e < 4; e++) hh[e] = (short)f2bf(v[e]);
            *(s16x4*)&As[arow][acol + g * 4] = hh;
        }
        *(bf16x8*)&Bhs[brow][bcol]     = *(const bf16x8*)(Bp + k0);
        *(bf16x8*)&Bhs[brow][bcol + 8] = *(const bf16x8*)(Bp + k0 + 8);
        __syncthreads();

        bf16x8 af[2], bhf[4];
        #pragma unroll
        for (int i = 0; i < 2; i++)
            af[i] = *(const bf16x8*)&As[wrow + i * 16 + lr][lk];
        #pragma unroll
        for (int j = 0; j < 4; j++)
            bhf[j] = *(const bf16x8*)&Bhs[wcol + j * 16 + lr][lk];
        #pragma unroll
        for (int i = 0; i < 2; i++)
            #pragma unroll
            for (int j = 0; j < 4; j++)
                acc[i][j] = __builtin_amdgcn_mfma_f32_16x16x32_bf16(af[i], bhf[j], acc[i][j], 0, 0, 0);
        __syncthreads();
    }

    #pragma unroll
    for (int j = 0; j < 4; j++) {
        int col = n0 + wcol + j * 16 + lr;
        float bb = bias[col];
        int h = col >> 5, d = col & 31;
        #pragma unroll
        for (int i = 0; i < 2; i++) {
            int gmb = m0 + wrow + i * 16 + quad * 4;
            #pragma unroll
            for (int r = 0; r < 4; r++) {
                int gm = gmb + r;
                if (gm < M) {
                    float val = acc[i][j][r] + bb;
                    int b = (gm >= NV) ? 1 : 0;
                    int pix = gm - b * NV;
                    Cv[((size_t)(b * 8 + h) * NV + pix) * 32 + d] =
                        __half_as_ushort(__float2half(val));
                }
            }
        }
    }
}

// ---------------------------------------------------------------------------
// Query-projection GEMM (A = query + qpos). [FROZEN r13 body; split r18.]
// ---------------------------------------------------------------------------
__global__ __launch_bounds__(256) void gemm_query(
    const float* __restrict__ query, const float* __restrict__ qpos,
    const ushort* __restrict__ Bt, const float* __restrict__ bias,
    float* __restrict__ C0, float* __restrict__ C1)
{
    __shared__ short As[64][40], Bhs[128][40];

    const int tid = threadIdx.x;

    const int q0 = blockIdx.x;
    const int xcd = q0 & 7, idx = q0 >> 3;
    const int bid = (xcd < 3) ? (xcd * 118 + idx)
                              : (3 * 118 + (xcd - 3) * 117 + idx);

    const int mblk = bid / 3, npan = bid % 3;
    const int M  = BS * NQ;
    const int m0 = mblk * 64;
    const int n0 = npan * 128;
    const int nbase = 256 + n0;

    const int arow = tid >> 2;
    const int acol = (tid & 3) * 8;
    const bool aval = (m0 + arow) < M;
    const float* Ap  = query + (size_t)(m0 + arow) * 256 + acol;
    const float* A2p = qpos  + (size_t)(m0 + arow) * 256 + acol;
    const int brow = tid >> 1;
    const int bcol = (tid & 1) * 16;
    const ushort* Bp = Bt + (size_t)(nbase + brow) * 256 + bcol;

    const int lane = tid & 63, wave = tid >> 6;
    const int wrow = (wave >> 1) * 32, wcol = (wave & 1) * 64;
    const int lr = lane & 15, quad = lane >> 4, lk = quad * 8;

    f32x4 acc[2][4] = {};

    for (int k0 = 0; k0 < 256; k0 += 32) {
        #pragma unroll
        for (int g = 0; g < 2; g++) {
            f32x4 v = {};
            if (aval) {
                v = *(const f32x4*)(Ap + k0 + g * 4);
                v += *(const f32x4*)(A2p + k0 + g * 4);
            }
            s16x4 hh;
            #pragma unroll
            for (int e = 0; e < 4; e++) hh[e] = (short)f2bf(v[e]);
            *(s16x4*)&As[arow][acol + g * 4] = hh;
        }
        *(bf16x8*)&Bhs[brow][bcol]     = *(const bf16x8*)(Bp + k0);
        *(bf16x8*)&Bhs[brow][bcol + 8] = *(const bf16x8*)(Bp + k0 + 8);
        __syncthreads();

        bf16x8 af[2], bhf[4];
        #pragma unroll
        for (int i = 0; i < 2; i++)
            af[i] = *(const bf16x8*)&As[wrow + i * 16 + lr][lk];
        #pragma unroll
        for (int j = 0; j < 4; j++)
            bhf[j] = *(const bf16x8*)&Bhs[wcol + j * 16 + lr][lk];
        #pragma unroll
        for (int i = 0; i < 2; i++)
            #pragma unroll
            for (int j = 0; j < 4; j++)
                acc[i][j] = __builtin_amdgcn_mfma_f32_16x16x32_bf16(af[i], bhf[j], acc[i][j], 0, 0, 0);
        __syncthreads();
    }

    #pragma unroll
    for (int j = 0; j < 4; j++) {
        int cc = wcol + j * 16 + lr;
        int col = n0 + cc;
        float bb = bias[nbase + cc];
        #pragma unroll
        for (int i = 0; i < 2; i++) {
            int gmb = m0 + wrow + i * 16 + quad * 4;
            #pragma unroll
            for (int r = 0; r < 4; r++) {
                int gm = gmb + r;
                if (gm < M) {
                    float val = acc[i][j][r] + bb;
                    if (col < 256) C0[(size_t)gm * 256 + col] = val;
                    else           C1[(size_t)gm * 128 + (col - 256)] = val;
                }
            }
        }
    }
}

// ---------------------------------------------------------------------------
// Fused softmax + location + bilinear gather. ROUND-19: r10 counters showed
// occupancy 25% / VALU 44% / HBM 15% -> LDS-capped latency bind (33KB ->
// <=4 blocks/CU, ~2 measured). Fix: compress per-point LDS 64B -> 20B.
// The 4 corner offsets derive from one: off_c = off0 + (c&1)*dx + (c&2?dy:0),
// dx = 64*(xc1-xc0) in {0,64}, dy = 64*W*(yc1-yc0) (clamp-aware). Pack
// off0/64 (19b) | dx flag (1b) | W*(yc1-yc0) (12b) into ONE u32 + f32x4
// weights (fp32 kept: fp16 weights risk the absmax budget).
// LDS: s_o[64][17] u32 (4.3KB) + s_w[64][17] f32x4 (17.4KB) = 21.8KB
// -> 7 blocks/CU (28 waves, matches VGPR limit). Reads: 16 b32 (17-pad ->
// conflict-free) + 16 b128 (2-way, free) per thread, was 64 b64.
// Partition/XCD pinning unchanged [r17 proven].
// ---------------------------------------------------------------------------
__global__ __launch_bounds__(256) void sample4(
    const ushort* __restrict__ v, const float* __restrict__ off,
    const float* __restrict__ attn, const float* __restrict__ refp,
    float* __restrict__ out)
{
    __shared__ unsigned s_o[64][17];   // packed: off0/64 | dx<<19 | dyW<<20
    __shared__ f32x4    s_w[64][17];   // 4 corner weights

    const int t = threadIdx.x;
    const int combo = blockIdx.x & 15;     // (b, head) -> fixed XCD slot
    const int qgrp  = blockIdx.x >> 4;     // 0..156
    const int b  = combo & 1;
    const int h0 = combo >> 1;             // 0..7

    const int q = t >> 2;                  // 0..63
    const int l = t & 3;                   // level owned by this thread
    const int qt = qgrp * 64 + q;
    const bool valid = qt < NQ;
    const size_t bq = (size_t)b * NQ + (valid ? qt : NQ - 1);

    {
        f32x4 lg = *(const f32x4*)(attn + bq * 128 + h0 * 16 + l * 4);
        float mx = fmaxf(fmaxf(lg[0], lg[1]), fmaxf(lg[2], lg[3]));
        mx = fmaxf(mx, __shfl_xor(mx, 1, 4));
        mx = fmaxf(mx, __shfl_xor(mx, 2, 4));
        float e0 = __expf(lg[0] - mx), e1 = __expf(lg[1] - mx);
        float e2 = __expf(lg[2] - mx), e3 = __expf(lg[3] - mx);
        float s = e0 + e1 + e2 + e3;
        s += __shfl_xor(s, 1, 4);
        s += __shfl_xor(s, 2, 4);
        float inv = 1.f / s;

        const float Wl = (l == 0) ? 160.f : (l == 1) ? 80.f : (l == 2) ? 40.f : 20.f;
        const float Hl = (l == 0) ? 92.f  : (l == 1) ? 46.f : (l == 2) ? 23.f : 12.f;
        const int  stl = (l == 0) ? 0 : (l == 1) ? 14720 : (l == 2) ? 18400 : 19320;
        const int  Wi_ = (int)Wl, Hi_ = (int)Hl;
        const int base = (b * 8 + h0) * NV + stl;    // in 64B lines

        f32x4 of0 = *(const f32x4*)(off + bq * 256 + h0 * 32 + l * 8);
        f32x4 of1 = *(const f32x4*)(off + bq * 256 + h0 * 32 + l * 8 + 4);
        f32x4 r0  = *(const f32x4*)(refp + bq * 8);
        f32x4 r1  = *(const f32x4*)(refp + bq * 8 + 4);

        float ws[4]  = {e0 * inv, e1 * inv, e2 * inv, e3 * inv};
        float oxs[4] = {of0[0], of0[2], of1[0], of1[2]};
        float oys[4] = {of0[1], of0[3], of1[1], of1[3]};
        float rxs[4] = {r0[0], r0[2], r1[0], r1[2]};
        float rys[4] = {r0[1], r0[3], r1[1], r1[3]};

        #pragma unroll
        for (int p = 0; p < 4; p++) {
            float x = rxs[p] * Wl + oxs[p] - 0.5f;
            float y = rys[p] * Hl + oys[p] - 0.5f;
            float x0f = floorf(x), y0f = floorf(y);
            float wx1 = x - x0f, wy1 = y - y0f;
            float wx0 = 1.f - wx1, wy0 = 1.f - wy1;
            int x0 = (int)x0f, y0 = (int)y0f;
            float mx0 = ((unsigned)x0       < (unsigned)Wi_) ? 1.f : 0.f;
            float mx1 = ((unsigned)(x0 + 1) < (unsigned)Wi_) ? 1.f : 0.f;
            float my0 = ((unsigned)y0       < (unsigned)Hi_) ? 1.f : 0.f;
            float my1 = ((unsigned)(y0 + 1) < (unsigned)Hi_) ? 1.f : 0.f;
            int xc0 = min(max(x0, 0), Wi_ - 1);
            int xc1 = min(max(x0 + 1, 0), Wi_ - 1);
            int yc0 = min(max(y0, 0), Hi_ - 1);
            int yc1 = min(max(y0 + 1, 0), Hi_ - 1);
            float w = ws[p];
            int pt = l * 4 + p;
            unsigned off0 = (unsigned)(base + yc0 * Wi_ + xc0);
            unsigned dxf  = (unsigned)(xc1 - xc0);            // 0/1
            unsigned dyW  = (unsigned)((yc1 - yc0) * Wi_);    // 0/W
            s_o[q][pt] = off0 | (dxf << 19) | (dyW << 20);
            f32x4 wv = {w * wy0 * wx0 * my0 * mx0,
                        w * wy0 * wx1 * my0 * mx1,
                        w * wy1 * wx0 * my1 * mx0,
                        w * wy1 * wx1 * my1 * mx1};
            s_w[q][pt] = wv;
        }
    }
    __syncthreads();

    // ---- phase 2: 4 lanes per q, 16B per lane per corner ----
    const char* vb = (const char*)v + l * 16;   // this lane's 8 channels

    float a0 = 0.f, a1 = 0.f, a2 = 0.f, a3 = 0.f;
    float a4 = 0.f, a5 = 0.f, a6 = 0.f, a7 = 0.f;

    #pragma unroll
    for (int ib = 0; ib < 4; ib++) {            // 4 points (16 corners) per ib
        unsigned uu[4]; f32x4 ww[4];
        #pragma unroll
        for (int c = 0; c < 4; c++) {
            uu[c] = s_o[q][ib * 4 + c];
            ww[c] = s_w[q][ib * 4 + c];
        }

        u16x8 d[16];
        #pragma unroll
        for (int i = 0; i < 4; i++) {
            int o0 = (int)(uu[i] & 0x7FFFFu) << 6;
            int dx = (int)((uu[i] >> 19) & 1u) << 6;
            int dy = (int)(uu[i] >> 20) << 6;
            d[i * 4 + 0] = *(const u16x8*)(vb + o0);
            d[i * 4 + 1] = *(const u16x8*)(vb + o0 + dx);
            d[i * 4 + 2] = *(const u16x8*)(vb + o0 + dy);
            d[i * 4 + 3] = *(const u16x8*)(vb + o0 + dx + dy);
        }

        #pragma unroll
        for (int i = 0; i < 16; i++) {
            float w = ww[i >> 2][i & 3];
            const __half2* hp = (const __half2*)&d[i];
            float2 f0 = __half22float2(hp[0]);
            float2 f1 = __half22float2(hp[1]);
            float2 f2 = __half22float2(hp[2]);
            float2 f3 = __half22float2(hp[3]);
            a0 += w * f0.x; a1 += w * f0.y;
            a2 += w * f1.x; a3 += w * f1.y;
            a4 += w * f2.x; a5 += w * f2.y;
            a6 += w * f3.x; a7 += w * f3.y;
        }
    }

    if (valid) {
        float* op = out + bq * 256 + h0 * 32 + l * 8;
        f32x4 o0 = {a0, a1, a2, a3}, o1 = {a4, a5, a6, a7};
        *(f32x4*)op       = o0;
        *(f32x4*)(op + 4) = o1;
    }
}

extern "C" void kernel_launch(void* const* d_in, const int* in_sizes, int n_in,
                              void* d_out, int out_size, void* d_ws, size_t ws_size,
                              hipStream_t stream) {
    const float* query     = (const float*)d_in[0];
    const float* value     = (const float*)d_in[1];
    const float* query_pos = (const float*)d_in[2];
    const float* refp      = (const float*)d_in[3];
    const float* W_val     = (const float*)d_in[4];
    const float* b_val     = (const float*)d_in[5];
    const float* W_off     = (const float*)d_in[6];
    const float* b_off     = (const float*)d_in[7];
    const float* W_attn    = (const float*)d_in[8];
    const float* b_attn    = (const float*)d_in[9];
    float* out = (float*)d_out;

    char* w = (char*)d_ws;
    float*  off    = (float*)w;   w += 20480000;   // 20000 x 256 fp32
    float*  attn   = (float*)w;   w += 10240000;   // 20000 x 128 fp32
    ushort* vp_bf  = (ushort*)w;  w += 20029440;   // planar (b,h,NV,32) fp16
    ushort* Bt     = (ushort*)w;  w += 327680;     // 640 x 256 bf16
    float*  bias_c = (float*)w;   w += 2560;

    convert_W<<<640, 256, 0, stream>>>(W_val, W_off, W_attn, b_val, b_off, b_attn,
                                       Bt, bias_c);

    gemm_val<<<1224, 256, 0, stream>>>(value, Bt, bias_c, vp_bf);
    gemm_query<<<939, 256, 0, stream>>>(query, query_pos, Bt, bias_c, off, attn);

    // 64 queries x 1 head per block; 157 q-groups x 16 (b,h) combos
    sample4<<<157 * 16, 256, 0, stream>>>(vp_bf, off, attn, refp, out);
}

// Round 12
// 202.126 us; speedup vs baseline: 1.0117x; 1.0117x over previous
//
#include <hip/hip_runtime.h>
#include <hip/hip_fp16.h>

#define NQ 10000
#define BS 2
#define NV 19560
#define NH 8
#define HD 32
#define EMB 256

typedef __attribute__((ext_vector_type(8))) short bf16x8;
typedef __attribute__((ext_vector_type(8))) unsigned short u16x8;
typedef __attribute__((ext_vector_type(4))) float f32x4;
typedef __attribute__((ext_vector_type(4))) short s16x4;

__device__ __forceinline__ unsigned short f2bf(float x) {
    unsigned u = __float_as_uint(x);
    u += 0x7FFFu + ((u >> 16) & 1u);       // RNE
    return (unsigned short)(u >> 16);
}

// ---------------------------------------------------------------------------
// Transpose weights into Bt[n][k] bf16 + concat biases. [proven]
// ---------------------------------------------------------------------------
__global__ __launch_bounds__(256) void convert_W(
    const float* __restrict__ Wv, const float* __restrict__ Wo,
    const float* __restrict__ Wa, const float* __restrict__ bv,
    const float* __restrict__ bo, const float* __restrict__ ba,
    ushort* __restrict__ Bt, float* __restrict__ bias) {
    int n = blockIdx.x;      // 0..639
    int k = threadIdx.x;     // 0..255
    float x;
    if (n < 256)       x = Wv[k * 256 + n];
    else if (n < 512)  x = Wo[k * 256 + (n - 256)];
    else               x = Wa[k * 128 + (n - 512)];
    Bt[n * 256 + k] = f2bf(x);
    if (k == 0)
        bias[n] = (n < 256) ? bv[n] : (n < 512) ? bo[n - 256] : ba[n - 512];
}

// ---------------------------------------------------------------------------
// Fused GEMM. [RE-FUSED r16 body, measured 55.8-56.3us: r9 2-barrier 64x128
// + T1 remap + fp16 Cv store. The r18 split cost 3-4us total (199.8 fused vs
// 203-204.5 split) and its diagnostic purpose is served. FROZEN — ledger:
// r10 119 / r11 105 / r12 68 / r15 85 vs this 56.]
// ---------------------------------------------------------------------------
__global__ __launch_bounds__(256) void gemm_fused(
    const float* __restrict__ value, const float* __restrict__ query,
    const float* __restrict__ qpos, const ushort* __restrict__ Bt,
    const float* __restrict__ bias,
    ushort* __restrict__ Cv, float* __restrict__ C0, float* __restrict__ C1)
{
    __shared__ short As[64][40], Bhs[128][40];  // pad 32->40

    const int tid = threadIdx.x;

    // ---- T1: XCD-aware bijective remap [r13 proven] ----
    const int bid0 = blockIdx.x;
    int bid;
    if (bid0 < 1224) {
        bid = (bid0 & 7) * 153 + (bid0 >> 3);              // 1224 = 8*153
    } else {
        int q = bid0 - 1224;                               // 939 = 8*117+3
        int xcd = q & 7, idx = q >> 3;
        int orig = (xcd < 3) ? (xcd * 118 + idx)
                             : (3 * 118 + (xcd - 3) * 117 + idx);
        bid = 1224 + orig;
    }

    bool isval; int mblk, npan;
    if (bid < 1224) { isval = true;  mblk = bid >> 1; npan = bid & 1; }
    else { int q = bid - 1224; isval = false; mblk = q / 3; npan = q % 3; }

    const int M  = isval ? (BS * NV) : (BS * NQ);
    const int m0 = mblk * 64;
    const int n0 = npan * 128;
    const int nbase = (isval ? 0 : 256) + n0;

    const float* A = isval ? value : query;

    const int arow = tid >> 2;
    const int acol = (tid & 3) * 8;
    const bool aval = (m0 + arow) < M;
    const float* Ap  = A    + (size_t)(m0 + arow) * 256 + acol;
    const float* A2p = qpos + (size_t)(m0 + arow) * 256 + acol;
    const int brow = tid >> 1;
    const int bcol = (tid & 1) * 16;
    const ushort* Bp = Bt + (size_t)(nbase + brow) * 256 + bcol;

    const int lane = tid & 63, wave = tid >> 6;
    const int wrow = (wave >> 1) * 32, wcol = (wave & 1) * 64;
    const int lr = lane & 15, quad = lane >> 4, lk = quad * 8;

    f32x4 acc[2][4] = {};

    for (int k0 = 0; k0 < 256; k0 += 32) {
        #pragma unroll
        for (int g = 0; g < 2; g++) {
            f32x4 v = {};
            if (aval) {
                v = *(const f32x4*)(Ap + k0 + g * 4);
                if (!isval) v += *(const f32x4*)(A2p + k0 + g * 4);
            }
            s16x4 hh;
            #pragma unroll
            for (int e = 0; e < 4; e++) hh[e] = (short)f2bf(v[e]);
            *(s16x4*)&As[arow][acol + g * 4] = hh;
        }
        *(bf16x8*)&Bhs[brow][bcol]     = *(const bf16x8*)(Bp + k0);
        *(bf16x8*)&Bhs[brow][bcol + 8] = *(const bf16x8*)(Bp + k0 + 8);
        __syncthreads();

        bf16x8 af[2], bhf[4];
        #pragma unroll
        for (int i = 0; i < 2; i++)
            af[i] = *(const bf16x8*)&As[wrow + i * 16 + lr][lk];
        #pragma unroll
        for (int j = 0; j < 4; j++)
            bhf[j] = *(const bf16x8*)&Bhs[wcol + j * 16 + lr][lk];
        #pragma unroll
        for (int i = 0; i < 2; i++)
            #pragma unroll
            for (int j = 0; j < 4; j++)
                acc[i][j] = __builtin_amdgcn_mfma_f32_16x16x32_bf16(af[i], bhf[j], acc[i][j], 0, 0, 0);
        __syncthreads();
    }

    #pragma unroll
    for (int j = 0; j < 4; j++) {
        int cc = wcol + j * 16 + lr;
        int col = n0 + cc;
        float bb = bias[nbase + cc];
        #pragma unroll
        for (int i = 0; i < 2; i++) {
            int gmb = m0 + wrow + i * 16 + quad * 4;
            #pragma unroll
            for (int r = 0; r < 4; r++) {
                int gm = gmb + r;
                if (gm < M) {
                    float val = acc[i][j][r] + bb;
                    if (isval) {
                        int h = col >> 5, d = col & 31;
                        int b = (gm >= NV) ? 1 : 0;
                        int pix = gm - b * NV;
                        Cv[((size_t)(b * 8 + h) * NV + pix) * 32 + d] =
                            __half_as_ushort(__float2half(val));
                    } else {
                        if (col < 256) C0[(size_t)gm * 256 + col] = val;
                        else           C1[(size_t)gm * 128 + (col - 256)] = val;
                    }
                }
            }
        }
    }
}

// ---------------------------------------------------------------------------
// Fused softmax + location + bilinear gather. ROUND-20: r19 proved occupancy
// (25->49%) and conflicts (1.9M->0.4M) are NOT the limiter (dur flat 45->46).
// The VGPR_Count=40 counter exposed the real bind: plain launch_bounds(256)
// targets 8 waves/SIMD -> 64-VGPR budget -> compiler serialized the gathers
// to ~4-6 in flight per wave. Latency-bound with starved MLP (need ~300
// line-reqs in flight/CU, have ~100). Fix:
//  - __launch_bounds__(256, 4): 4 waves/EU floor -> 128-VGPR budget.
//  - explicit 2-deep software pipeline: two named 8-corner buffers dA/dB;
//    each FMA block overlaps the NEXT batch's 8 gathers (static indexing).
// Phase 1, compressed LDS (21.8KB), partition, XCD pinning: r19 verbatim.
// ---------------------------------------------------------------------------
__global__ __launch_bounds__(256, 4) void sample4(
    const ushort* __restrict__ v, const float* __restrict__ off,
    const float* __restrict__ attn, const float* __restrict__ refp,
    float* __restrict__ out)
{
    __shared__ unsigned s_o[64][17];   // packed: off0/64 | dx<<19 | dyW<<20
    __shared__ f32x4    s_w[64][17];   // 4 corner weights

    const int t = threadIdx.x;
    const int combo = blockIdx.x & 15;     // (b, head) -> fixed XCD slot
    const int qgrp  = blockIdx.x >> 4;     // 0..156
    const int b  = combo & 1;
    const int h0 = combo >> 1;             // 0..7

    const int q = t >> 2;                  // 0..63
    const int l = t & 3;                   // level owned by this thread
    const int qt = qgrp * 64 + q;
    const bool valid = qt < NQ;
    const size_t bq = (size_t)b * NQ + (valid ? qt : NQ - 1);

    {
        f32x4 lg = *(const f32x4*)(attn + bq * 128 + h0 * 16 + l * 4);
        float mx = fmaxf(fmaxf(lg[0], lg[1]), fmaxf(lg[2], lg[3]));
        mx = fmaxf(mx, __shfl_xor(mx, 1, 4));
        mx = fmaxf(mx, __shfl_xor(mx, 2, 4));
        float e0 = __expf(lg[0] - mx), e1 = __expf(lg[1] - mx);
        float e2 = __expf(lg[2] - mx), e3 = __expf(lg[3] - mx);
        float s = e0 + e1 + e2 + e3;
        s += __shfl_xor(s, 1, 4);
        s += __shfl_xor(s, 2, 4);
        float inv = 1.f / s;

        const float Wl = (l == 0) ? 160.f : (l == 1) ? 80.f : (l == 2) ? 40.f : 20.f;
        const float Hl = (l == 0) ? 92.f  : (l == 1) ? 46.f : (l == 2) ? 23.f : 12.f;
        const int  stl = (l == 0) ? 0 : (l == 1) ? 14720 : (l == 2) ? 18400 : 19320;
        const int  Wi_ = (int)Wl, Hi_ = (int)Hl;
        const int base = (b * 8 + h0) * NV + stl;    // in 64B lines

        f32x4 of0 = *(const f32x4*)(off + bq * 256 + h0 * 32 + l * 8);
        f32x4 of1 = *(const f32x4*)(off + bq * 256 + h0 * 32 + l * 8 + 4);
        f32x4 r0  = *(const f32x4*)(refp + bq * 8);
        f32x4 r1  = *(const f32x4*)(refp + bq * 8 + 4);

        float ws[4]  = {e0 * inv, e1 * inv, e2 * inv, e3 * inv};
        float oxs[4] = {of0[0], of0[2], of1[0], of1[2]};
        float oys[4] = {of0[1], of0[3], of1[1], of1[3]};
        float rxs[4] = {r0[0], r0[2], r1[0], r1[2]};
        float rys[4] = {r0[1], r0[3], r1[1], r1[3]};

        #pragma unroll
        for (int p = 0; p < 4; p++) {
            float x = rxs[p] * Wl + oxs[p] - 0.5f;
            float y = rys[p] * Hl + oys[p] - 0.5f;
            float x0f = floorf(x), y0f = floorf(y);
            float wx1 = x - x0f, wy1 = y - y0f;
            float wx0 = 1.f - wx1, wy0 = 1.f - wy1;
            int x0 = (int)x0f, y0 = (int)y0f;
            float mx0 = ((unsigned)x0       < (unsigned)Wi_) ? 1.f : 0.f;
            float mx1 = ((unsigned)(x0 + 1) < (unsigned)Wi_) ? 1.f : 0.f;
            float my0 = ((unsigned)y0       < (unsigned)Hi_) ? 1.f : 0.f;
            float my1 = ((unsigned)(y0 + 1) < (unsigned)Hi_) ? 1.f : 0.f;
            int xc0 = min(max(x0, 0), Wi_ - 1);
            int xc1 = min(max(x0 + 1, 0), Wi_ - 1);
            int yc0 = min(max(y0, 0), Hi_ - 1);
            int yc1 = min(max(y0 + 1, 0), Hi_ - 1);
            float w = ws[p];
            int pt = l * 4 + p;
            unsigned off0 = (unsigned)(base + yc0 * Wi_ + xc0);
            unsigned dxf  = (unsigned)(xc1 - xc0);            // 0/1
            unsigned dyW  = (unsigned)((yc1 - yc0) * Wi_);    // 0/W
            s_o[q][pt] = off0 | (dxf << 19) | (dyW << 20);
            f32x4 wv = {w * wy0 * wx0 * my0 * mx0,
                        w * wy0 * wx1 * my0 * mx1,
                        w * wy1 * wx0 * my1 * mx0,
                        w * wy1 * wx1 * my1 * mx1};
            s_w[q][pt] = wv;
        }
    }
    __syncthreads();

    // ---- phase 2: 4 lanes per q, 16B per lane per corner ----
    const char* vb = (const char*)v + l * 16;   // this lane's 8 channels

    float a0 = 0.f, a1 = 0.f, a2 = 0.f, a3 = 0.f;
    float a4 = 0.f, a5 = 0.f, a6 = 0.f, a7 = 0.f;

    // 8 batches of 2 points (8 corners); dA/dB double-buffer so every FMA
    // block runs with the next batch's 8 gathers in flight.
#define LOADB(d, k) { \
    unsigned ua = s_o[q][(k) * 2], ub = s_o[q][(k) * 2 + 1]; \
    int oa = (int)(ua & 0x7FFFFu) << 6; \
    int dxa = (int)((ua >> 19) & 1u) << 6; \
    int dya = (int)(ua >> 20) << 6; \
    int ob = (int)(ub & 0x7FFFFu) << 6; \
    int dxb = (int)((ub >> 19) & 1u) << 6; \
    int dyb = (int)(ub >> 20) << 6; \
    d[0] = *(const u16x8*)(vb + oa); \
    d[1] = *(const u16x8*)(vb + oa + dxa); \
    d[2] = *(const u16x8*)(vb + oa + dya); \
    d[3] = *(const u16x8*)(vb + oa + dxa + dya); \
    d[4] = *(const u16x8*)(vb + ob); \
    d[5] = *(const u16x8*)(vb + ob + dxb); \
    d[6] = *(const u16x8*)(vb + ob + dyb); \
    d[7] = *(const u16x8*)(vb + ob + dxb + dyb); }

#define FMAB(d, k) { \
    f32x4 wa = s_w[q][(k) * 2], wb = s_w[q][(k) * 2 + 1]; \
    _Pragma("unroll") \
    for (int i = 0; i < 8; i++) { \
        float w = (i < 4) ? wa[i] : wb[i - 4]; \
        const __half2* hp = (const __half2*)&d[i]; \
        float2 f0 = __half22float2(hp[0]); \
        float2 f1 = __half22float2(hp[1]); \
        float2 f2 = __half22float2(hp[2]); \
        float2 f3 = __half22float2(hp[3]); \
        a0 += w * f0.x; a1 += w * f0.y; \
        a2 += w * f1.x; a3 += w * f1.y; \
        a4 += w * f2.x; a5 += w * f2.y; \
        a6 += w * f3.x; a7 += w * f3.y; } }

    {
        u16x8 dA[8], dB[8];
        LOADB(dA, 0);
        LOADB(dB, 1);
        FMAB(dA, 0);
        LOADB(dA, 2);
        FMAB(dB, 1);
        LOADB(dB, 3);
        FMAB(dA, 2);
        LOADB(dA, 4);
        FMAB(dB, 3);
        LOADB(dB, 5);
        FMAB(dA, 4);
        LOADB(dA, 6);
        FMAB(dB, 5);
        LOADB(dB, 7);
        FMAB(dA, 6);
        FMAB(dB, 7);
    }
#undef LOADB
#undef FMAB

    if (valid) {
        float* op = out + bq * 256 + h0 * 32 + l * 8;
        f32x4 o0 = {a0, a1, a2, a3}, o1 = {a4, a5, a6, a7};
        *(f32x4*)op       = o0;
        *(f32x4*)(op + 4) = o1;
    }
}

extern "C" void kernel_launch(void* const* d_in, const int* in_sizes, int n_in,
                              void* d_out, int out_size, void* d_ws, size_t ws_size,
                              hipStream_t stream) {
    const float* query     = (const float*)d_in[0];
    const float* value     = (const float*)d_in[1];
    const float* query_pos = (const float*)d_in[2];
    const float* refp      = (const float*)d_in[3];
    const float* W_val     = (const float*)d_in[4];
    const float* b_val     = (const float*)d_in[5];
    const float* W_off     = (const float*)d_in[6];
    const float* b_off     = (const float*)d_in[7];
    const float* W_attn    = (const float*)d_in[8];
    const float* b_attn    = (const float*)d_in[9];
    float* out = (float*)d_out;

    char* w = (char*)d_ws;
    float*  off    = (float*)w;   w += 20480000;   // 20000 x 256 fp32
    float*  attn   = (float*)w;   w += 10240000;   // 20000 x 128 fp32
    ushort* vp_bf  = (ushort*)w;  w += 20029440;   // planar (b,h,NV,32) fp16
    ushort* Bt     = (ushort*)w;  w += 327680;     // 640 x 256 bf16
    float*  bias_c = (float*)w;   w += 2560;

    convert_W<<<640, 256, 0, stream>>>(W_val, W_off, W_attn, b_val, b_off, b_attn,
                                       Bt, bias_c);

    // one dispatch: value-proj (1224 blocks) + query-proj (939 blocks)
    gemm_fused<<<1224 + 939, 256, 0, stream>>>(value, query, query_pos, Bt, bias_c,
                                               vp_bf, off, attn);

    // 64 queries x 1 head per block; 157 q-groups x 16 (b,h) combos
    sample4<<<157 * 16, 256, 0, stream>>>(vp_bf, off, attn, refp, out);
}